// Round 1
// baseline (1287.145 us; speedup 1.0000x reference)
//
#include <hip/hip_runtime.h>
#include <math.h>

// OHNM loss: pos BCE sum + top-k(600000) negative softplus sum, mean over 800000.
// Strategy: exact radix-select (3-level histogram on monotone uint32 key) for the
// k-th largest negative value; sum softplus over strictly-greater + ties*softplus(t).

#define NBINS1 4096
#define NBINS2 1024
#define CTRL_BYTES 32768

struct Ctrl {
    unsigned hist1[NBINS1];   // top-12-bit histogram (negatives)
    unsigned hist2[NBINS2];   // mid-10-bit histogram (candidates)
    unsigned hist3[NBINS2];   // low-10-bit histogram (candidates, mid==b2)
    float    pos_sum;         // sum softplus(-x) over positives
    float    neg_sure;        // sum softplus(x) over negatives with bin > b1
    unsigned cand_count;
    unsigned Kneg;            // 3 * pos_num
    unsigned b1, c1, r1;      // scan level-1 out: bin, count-above, remaining rank
    unsigned b2, c2, r2;
    unsigned b3, c3, r3;
};

__device__ __forceinline__ unsigned f2key(float x) {
    unsigned u = __float_as_uint(x);
    return (u & 0x80000000u) ? ~u : (u | 0x80000000u);
}
__device__ __forceinline__ float key2f(unsigned k) {
    unsigned u = (k & 0x80000000u) ? (k & 0x7FFFFFFFu) : ~k;
    return __uint_as_float(u);
}
__device__ __forceinline__ float softplusf(float x) {
    return fmaxf(x, 0.0f) + log1pf(__expf(-fabsf(x)));
}

// ---------------- init: zero control region, stash Kneg ----------------
__global__ void k_init(unsigned* ws, const int* __restrict__ pos_num) {
    for (int i = threadIdx.x; i < CTRL_BYTES / 4; i += blockDim.x) ws[i] = 0u;
    __syncthreads();
    if (threadIdx.x == 0) {
        Ctrl* c = (Ctrl*)ws;
        c->Kneg = (unsigned)(pos_num[0] * 3);
    }
}

// ---------------- pass 1: hist of top-12 key bits + pos_sum ----------------
__global__ __launch_bounds__(256)
void k_hist1(const float* __restrict__ x, const float* __restrict__ y,
             Ctrl* __restrict__ ctrl, int n) {
    __shared__ unsigned h[NBINS1];
    __shared__ float red;
    for (int i = threadIdx.x; i < NBINS1; i += 256) h[i] = 0u;
    if (threadIdx.x == 0) red = 0.0f;
    __syncthreads();

    float ps = 0.0f;
    const int n4 = n >> 2;
    const float4* x4 = (const float4*)x;
    const float4* y4 = (const float4*)y;
    const int stride = gridDim.x * blockDim.x;
    for (int i = blockIdx.x * blockDim.x + threadIdx.x; i < n4; i += stride) {
        float4 xv = x4[i];
        float4 yv = y4[i];
        if (yv.x > 0.0f) ps += softplusf(-xv.x); else atomicAdd(&h[f2key(xv.x) >> 20], 1u);
        if (yv.y > 0.0f) ps += softplusf(-xv.y); else atomicAdd(&h[f2key(xv.y) >> 20], 1u);
        if (yv.z > 0.0f) ps += softplusf(-xv.z); else atomicAdd(&h[f2key(xv.z) >> 20], 1u);
        if (yv.w > 0.0f) ps += softplusf(-xv.w); else atomicAdd(&h[f2key(xv.w) >> 20], 1u);
    }
    // tail (n not multiple of 4)
    if (blockIdx.x == 0 && threadIdx.x == 0) {
        for (int i = n4 << 2; i < n; ++i) {
            float xs = x[i], ys = y[i];
            if (ys > 0.0f) ps += softplusf(-xs); else atomicAdd(&h[f2key(xs) >> 20], 1u);
        }
    }
    __syncthreads();
    atomicAdd(&red, ps);
    for (int i = threadIdx.x; i < NBINS1; i += 256) {
        unsigned v = h[i];
        if (v) atomicAdd(&ctrl->hist1[i], v);
    }
    __syncthreads();
    if (threadIdx.x == 0 && red != 0.0f) atomicAdd(&ctrl->pos_sum, red);
}

// ---------------- generic descending-order rank scan (1 block, 256 thr) -----
// finds first bin (descending) where cumulative count >= R.
// out3[0]=bin index, out3[1]=count strictly above, out3[2]=R-count_above (>=1)
__global__ __launch_bounds__(256)
void k_scan(const unsigned* __restrict__ hist, int nbins,
            const unsigned* __restrict__ rank_ptr, unsigned* __restrict__ out3) {
    __shared__ unsigned sums[256];
    const unsigned R = *rank_ptr;
    const int per = nbins / 256;
    const int t = threadIdx.x;
    unsigned local[16];
    unsigned s = 0;
    for (int j = 0; j < per; ++j) {
        local[j] = hist[nbins - 1 - (t * per + j)];
        s += local[j];
    }
    sums[t] = s;
    __syncthreads();
    for (int off = 1; off < 256; off <<= 1) {
        unsigned v = (t >= off) ? sums[t - off] : 0u;
        __syncthreads();
        sums[t] += v;
        __syncthreads();
    }
    const unsigned incl = sums[t];
    const unsigned excl = incl - s;
    if (excl < R && incl >= R) {
        unsigned cum = excl;
        for (int j = 0; j < per; ++j) {
            if (cum + local[j] >= R) {
                int d = t * per + j;
                out3[0] = (unsigned)(nbins - 1 - d);
                out3[1] = cum;
                out3[2] = R - cum;
                break;
            }
            cum += local[j];
        }
    }
}

// ---------------- pass 2: sure-sum (bin > b1) + compact candidates (bin==b1) --
__global__ __launch_bounds__(256)
void k_compact(const float* __restrict__ x, const float* __restrict__ y,
               Ctrl* __restrict__ ctrl, unsigned* __restrict__ cand,
               unsigned cap, int n) {
    __shared__ float red;
    if (threadIdx.x == 0) red = 0.0f;
    __syncthreads();
    const unsigned b1 = ctrl->b1;
    float ns = 0.0f;
    const int n4 = n >> 2;
    const float4* x4 = (const float4*)x;
    const float4* y4 = (const float4*)y;
    const int stride = gridDim.x * blockDim.x;
    for (int i = blockIdx.x * blockDim.x + threadIdx.x; i < n4; i += stride) {
        float4 xv = x4[i];
        float4 yv = y4[i];
        float xs[4] = {xv.x, xv.y, xv.z, xv.w};
        float yss[4] = {yv.x, yv.y, yv.z, yv.w};
#pragma unroll
        for (int c = 0; c < 4; ++c) {
            if (yss[c] == 0.0f) {
                unsigned k = f2key(xs[c]);
                unsigned b = k >> 20;
                if (b > b1) {
                    ns += softplusf(xs[c]);
                } else if (b == b1) {
                    unsigned idx = atomicAdd(&ctrl->cand_count, 1u);
                    if (idx < cap) cand[idx] = k;
                }
            }
        }
    }
    if (blockIdx.x == 0 && threadIdx.x == 0) {
        for (int i = n4 << 2; i < n; ++i) {
            float xs = x[i], ys = y[i];
            if (ys == 0.0f) {
                unsigned k = f2key(xs);
                unsigned b = k >> 20;
                if (b > b1) ns += softplusf(xs);
                else if (b == b1) {
                    unsigned idx = atomicAdd(&ctrl->cand_count, 1u);
                    if (idx < cap) cand[idx] = k;
                }
            }
        }
    }
    __syncthreads();
    atomicAdd(&red, ns);
    __syncthreads();
    if (threadIdx.x == 0 && red != 0.0f) atomicAdd(&ctrl->neg_sure, red);
}

// ---------------- candidate histograms (level 2: mid 10 bits; level 3: low) --
__global__ __launch_bounds__(256)
void k_candhist(const unsigned* __restrict__ cand, Ctrl* __restrict__ ctrl,
                unsigned cap, int level) {
    __shared__ unsigned h[NBINS2];
    for (int i = threadIdx.x; i < NBINS2; i += 256) h[i] = 0u;
    __syncthreads();
    const unsigned m0 = ctrl->cand_count;
    const unsigned m = m0 < cap ? m0 : cap;
    const unsigned b2 = ctrl->b2;
    const unsigned stride = gridDim.x * blockDim.x;
    for (unsigned i = blockIdx.x * blockDim.x + threadIdx.x; i < m; i += stride) {
        unsigned k = cand[i];
        if (level == 2) {
            atomicAdd(&h[(k >> 10) & 1023u], 1u);
        } else {
            if (((k >> 10) & 1023u) == b2) atomicAdd(&h[k & 1023u], 1u);
        }
    }
    __syncthreads();
    unsigned* g = (level == 2) ? ctrl->hist2 : ctrl->hist3;
    for (int i = threadIdx.x; i < NBINS2; i += 256) {
        unsigned v = h[i];
        if (v) atomicAdd(&g[i], v);
    }
}

// ---------------- final: sum softplus over candidates > t, combine -----------
__global__ __launch_bounds__(1024)
void k_final(const unsigned* __restrict__ cand, Ctrl* __restrict__ ctrl,
             unsigned cap, const int* __restrict__ pos_num,
             float* __restrict__ out) {
    __shared__ float red;
    if (threadIdx.x == 0) red = 0.0f;
    __syncthreads();
    const unsigned m0 = ctrl->cand_count;
    const unsigned m = m0 < cap ? m0 : cap;
    const unsigned t_key = (ctrl->b1 << 20) | (ctrl->b2 << 10) | ctrl->b3;
    float s = 0.0f;
    for (unsigned i = threadIdx.x; i < m; i += blockDim.x) {
        unsigned k = cand[i];
        if (k > t_key) s += softplusf(key2f(k));
    }
    atomicAdd(&red, s);
    __syncthreads();
    if (threadIdx.x == 0) {
        int p = pos_num[0];
        float ties = (float)ctrl->r3 * softplusf(key2f(t_key));
        float total = ctrl->pos_sum + ctrl->neg_sure + red + ties;
        out[0] = total / (float)(p + 3 * p);
    }
}

extern "C" void kernel_launch(void* const* d_in, const int* in_sizes, int n_in,
                              void* d_out, int out_size, void* d_ws, size_t ws_size,
                              hipStream_t stream) {
    const float* x = (const float*)d_in[0];
    const float* y = (const float*)d_in[1];
    const int* pos_num = (const int*)d_in[2];
    float* out = (float*)d_out;
    const int n = in_sizes[0];

    unsigned* ws = (unsigned*)d_ws;
    Ctrl* ctrl = (Ctrl*)d_ws;
    unsigned* cand = ws + CTRL_BYTES / 4;
    unsigned cap = (ws_size > (size_t)CTRL_BYTES)
                       ? (unsigned)((ws_size - CTRL_BYTES) / 4)
                       : 0u;

    unsigned* hist1 = ws + offsetof(Ctrl, hist1) / 4;
    unsigned* hist2 = ws + offsetof(Ctrl, hist2) / 4;
    unsigned* hist3 = ws + offsetof(Ctrl, hist3) / 4;
    unsigned* Kneg = ws + offsetof(Ctrl, Kneg) / 4;
    unsigned* b1o = ws + offsetof(Ctrl, b1) / 4;
    unsigned* r1o = ws + offsetof(Ctrl, r1) / 4;
    unsigned* b2o = ws + offsetof(Ctrl, b2) / 4;
    unsigned* r2o = ws + offsetof(Ctrl, r2) / 4;
    unsigned* b3o = ws + offsetof(Ctrl, b3) / 4;

    k_init<<<1, 1024, 0, stream>>>(ws, pos_num);
    k_hist1<<<1024, 256, 0, stream>>>(x, y, ctrl, n);
    k_scan<<<1, 256, 0, stream>>>(hist1, NBINS1, Kneg, b1o);
    k_compact<<<1024, 256, 0, stream>>>(x, y, ctrl, cand, cap, n);
    k_candhist<<<128, 256, 0, stream>>>(cand, ctrl, cap, 2);
    k_scan<<<1, 256, 0, stream>>>(hist2, NBINS2, r1o, b2o);
    k_candhist<<<128, 256, 0, stream>>>(cand, ctrl, cap, 3);
    k_scan<<<1, 256, 0, stream>>>(hist3, NBINS2, r2o, b3o);
    k_final<<<1, 1024, 0, stream>>>(cand, ctrl, cap, pos_num, out);
}

// Round 2
// 311.967 us; speedup vs baseline: 4.1259x; 4.1259x over previous
//
#include <hip/hip_runtime.h>
#include <math.h>

// OHNM loss: pos BCE sum + top-k(600000) negative softplus sum, mean over 800000.
// Exact radix-select (3-level histogram on monotone uint32 key) for the k-th
// largest negative value; sum softplus over strictly-greater + ties*softplus(t).
//
// R2 fix: k_compact candidate compaction now stages candidates in LDS and does
// ONE global atomicAdd per block (was: one per candidate -> 143K same-address
// device atomics -> 5 GB of cache-line ping-pong writes, 1 ms serialization).

#define NBINS1 4096
#define NBINS2 1024
#define CTRL_BYTES 32768
#define LBUF_CAP 4096

struct Ctrl {
    unsigned hist1[NBINS1];   // top-12-bit histogram (negatives)
    unsigned hist2[NBINS2];   // mid-10-bit histogram (candidates)
    unsigned hist3[NBINS2];   // low-10-bit histogram (candidates, mid==b2)
    float    pos_sum;         // sum softplus(-x) over positives
    float    neg_sure;        // sum softplus(x) over negatives with bin > b1
    unsigned cand_count;
    unsigned Kneg;            // 3 * pos_num
    unsigned b1, c1, r1;      // scan level-1 out: bin, count-above, remaining rank
    unsigned b2, c2, r2;
    unsigned b3, c3, r3;
};

__device__ __forceinline__ unsigned f2key(float x) {
    unsigned u = __float_as_uint(x);
    return (u & 0x80000000u) ? ~u : (u | 0x80000000u);
}
__device__ __forceinline__ float key2f(unsigned k) {
    unsigned u = (k & 0x80000000u) ? (k & 0x7FFFFFFFu) : ~k;
    return __uint_as_float(u);
}
__device__ __forceinline__ float softplusf(float x) {
    return fmaxf(x, 0.0f) + log1pf(__expf(-fabsf(x)));
}

// ---------------- init: zero control region, stash Kneg ----------------
__global__ void k_init(unsigned* ws, const int* __restrict__ pos_num) {
    for (int i = threadIdx.x; i < CTRL_BYTES / 4; i += blockDim.x) ws[i] = 0u;
    __syncthreads();
    if (threadIdx.x == 0) {
        Ctrl* c = (Ctrl*)ws;
        c->Kneg = (unsigned)(pos_num[0] * 3);
    }
}

// ---------------- pass 1: hist of top-12 key bits + pos_sum ----------------
__global__ __launch_bounds__(256)
void k_hist1(const float* __restrict__ x, const float* __restrict__ y,
             Ctrl* __restrict__ ctrl, int n) {
    __shared__ unsigned h[NBINS1];
    __shared__ float red;
    for (int i = threadIdx.x; i < NBINS1; i += 256) h[i] = 0u;
    if (threadIdx.x == 0) red = 0.0f;
    __syncthreads();

    float ps = 0.0f;
    const int n4 = n >> 2;
    const float4* x4 = (const float4*)x;
    const float4* y4 = (const float4*)y;
    const int stride = gridDim.x * blockDim.x;
    for (int i = blockIdx.x * blockDim.x + threadIdx.x; i < n4; i += stride) {
        float4 xv = x4[i];
        float4 yv = y4[i];
        if (yv.x > 0.0f) ps += softplusf(-xv.x); else atomicAdd(&h[f2key(xv.x) >> 20], 1u);
        if (yv.y > 0.0f) ps += softplusf(-xv.y); else atomicAdd(&h[f2key(xv.y) >> 20], 1u);
        if (yv.z > 0.0f) ps += softplusf(-xv.z); else atomicAdd(&h[f2key(xv.z) >> 20], 1u);
        if (yv.w > 0.0f) ps += softplusf(-xv.w); else atomicAdd(&h[f2key(xv.w) >> 20], 1u);
    }
    // tail (n not multiple of 4)
    if (blockIdx.x == 0 && threadIdx.x == 0) {
        for (int i = n4 << 2; i < n; ++i) {
            float xs = x[i], ys = y[i];
            if (ys > 0.0f) ps += softplusf(-xs); else atomicAdd(&h[f2key(xs) >> 20], 1u);
        }
    }
    __syncthreads();
    atomicAdd(&red, ps);
    for (int i = threadIdx.x; i < NBINS1; i += 256) {
        unsigned v = h[i];
        if (v) atomicAdd(&ctrl->hist1[i], v);
    }
    __syncthreads();
    if (threadIdx.x == 0 && red != 0.0f) atomicAdd(&ctrl->pos_sum, red);
}

// ---------------- generic descending-order rank scan (1 block, 256 thr) -----
// finds first bin (descending) where cumulative count >= R.
// out3[0]=bin index, out3[1]=count strictly above, out3[2]=R-count_above (>=1)
__global__ __launch_bounds__(256)
void k_scan(const unsigned* __restrict__ hist, int nbins,
            const unsigned* __restrict__ rank_ptr, unsigned* __restrict__ out3) {
    __shared__ unsigned sums[256];
    const unsigned R = *rank_ptr;
    const int per = nbins / 256;
    const int t = threadIdx.x;
    unsigned local[16];
    unsigned s = 0;
    for (int j = 0; j < per; ++j) {
        local[j] = hist[nbins - 1 - (t * per + j)];
        s += local[j];
    }
    sums[t] = s;
    __syncthreads();
    for (int off = 1; off < 256; off <<= 1) {
        unsigned v = (t >= off) ? sums[t - off] : 0u;
        __syncthreads();
        sums[t] += v;
        __syncthreads();
    }
    const unsigned incl = sums[t];
    const unsigned excl = incl - s;
    if (excl < R && incl >= R) {
        unsigned cum = excl;
        for (int j = 0; j < per; ++j) {
            if (cum + local[j] >= R) {
                int d = t * per + j;
                out3[0] = (unsigned)(nbins - 1 - d);
                out3[1] = cum;
                out3[2] = R - cum;
                break;
            }
            cum += local[j];
        }
    }
}

// ---------------- pass 2: sure-sum (bin > b1) + compact candidates (bin==b1) --
// Candidates staged in LDS; one global atomicAdd per block reserves the range.
__global__ __launch_bounds__(256)
void k_compact(const float* __restrict__ x, const float* __restrict__ y,
               Ctrl* __restrict__ ctrl, unsigned* __restrict__ cand,
               unsigned cap, int n) {
    __shared__ unsigned lbuf[LBUF_CAP];
    __shared__ unsigned lcount;
    __shared__ unsigned gbase;
    __shared__ float red;
    if (threadIdx.x == 0) { lcount = 0u; red = 0.0f; }
    __syncthreads();
    const unsigned b1 = ctrl->b1;
    float ns = 0.0f;
    const int n4 = n >> 2;
    const float4* x4 = (const float4*)x;
    const float4* y4 = (const float4*)y;
    const int stride = gridDim.x * blockDim.x;
    for (int i = blockIdx.x * blockDim.x + threadIdx.x; i < n4; i += stride) {
        float4 xv = x4[i];
        float4 yv = y4[i];
        float xs[4] = {xv.x, xv.y, xv.z, xv.w};
        float yss[4] = {yv.x, yv.y, yv.z, yv.w};
#pragma unroll
        for (int c = 0; c < 4; ++c) {
            if (yss[c] == 0.0f) {
                unsigned k = f2key(xs[c]);
                unsigned b = k >> 20;
                if (b > b1) {
                    ns += softplusf(xs[c]);
                } else if (b == b1) {
                    unsigned p = atomicAdd(&lcount, 1u);        // LDS atomic
                    if (p < LBUF_CAP) lbuf[p] = k;
                    else {  // overflow fallback (never expected: lambda ~140/block)
                        unsigned gi = atomicAdd(&ctrl->cand_count, 1u);
                        if (gi < cap) cand[gi] = k;
                    }
                }
            }
        }
    }
    if (blockIdx.x == 0 && threadIdx.x == 0) {
        for (int i = n4 << 2; i < n; ++i) {
            float xs = x[i], ys = y[i];
            if (ys == 0.0f) {
                unsigned k = f2key(xs);
                unsigned b = k >> 20;
                if (b > b1) ns += softplusf(xs);
                else if (b == b1) {
                    unsigned p = atomicAdd(&lcount, 1u);
                    if (p < LBUF_CAP) lbuf[p] = k;
                    else {
                        unsigned gi = atomicAdd(&ctrl->cand_count, 1u);
                        if (gi < cap) cand[gi] = k;
                    }
                }
            }
        }
    }
    __syncthreads();
    atomicAdd(&red, ns);
    const unsigned m = lcount < LBUF_CAP ? lcount : LBUF_CAP;
    if (threadIdx.x == 0) gbase = atomicAdd(&ctrl->cand_count, m);  // ONE per block
    __syncthreads();
    for (unsigned i = threadIdx.x; i < m; i += 256) {
        unsigned gi = gbase + i;
        if (gi < cap) cand[gi] = lbuf[i];
    }
    if (threadIdx.x == 0) atomicAdd(&ctrl->neg_sure, red);
}

// ---------------- candidate histograms (level 2: mid 10 bits; level 3: low) --
__global__ __launch_bounds__(256)
void k_candhist(const unsigned* __restrict__ cand, Ctrl* __restrict__ ctrl,
                unsigned cap, int level) {
    __shared__ unsigned h[NBINS2];
    for (int i = threadIdx.x; i < NBINS2; i += 256) h[i] = 0u;
    __syncthreads();
    const unsigned m0 = ctrl->cand_count;
    const unsigned m = m0 < cap ? m0 : cap;
    const unsigned b2 = ctrl->b2;
    const unsigned stride = gridDim.x * blockDim.x;
    for (unsigned i = blockIdx.x * blockDim.x + threadIdx.x; i < m; i += stride) {
        unsigned k = cand[i];
        if (level == 2) {
            atomicAdd(&h[(k >> 10) & 1023u], 1u);
        } else {
            if (((k >> 10) & 1023u) == b2) atomicAdd(&h[k & 1023u], 1u);
        }
    }
    __syncthreads();
    unsigned* g = (level == 2) ? ctrl->hist2 : ctrl->hist3;
    for (int i = threadIdx.x; i < NBINS2; i += 256) {
        unsigned v = h[i];
        if (v) atomicAdd(&g[i], v);
    }
}

// ---------------- final: sum softplus over candidates > t, combine -----------
__global__ __launch_bounds__(1024)
void k_final(const unsigned* __restrict__ cand, Ctrl* __restrict__ ctrl,
             unsigned cap, const int* __restrict__ pos_num,
             float* __restrict__ out) {
    __shared__ float red;
    if (threadIdx.x == 0) red = 0.0f;
    __syncthreads();
    const unsigned m0 = ctrl->cand_count;
    const unsigned m = m0 < cap ? m0 : cap;
    const unsigned t_key = (ctrl->b1 << 20) | (ctrl->b2 << 10) | ctrl->b3;
    float s = 0.0f;
    for (unsigned i = threadIdx.x; i < m; i += blockDim.x) {
        unsigned k = cand[i];
        if (k > t_key) s += softplusf(key2f(k));
    }
    atomicAdd(&red, s);
    __syncthreads();
    if (threadIdx.x == 0) {
        int p = pos_num[0];
        float ties = (float)ctrl->r3 * softplusf(key2f(t_key));
        float total = ctrl->pos_sum + ctrl->neg_sure + red + ties;
        out[0] = total / (float)(p + 3 * p);
    }
}

extern "C" void kernel_launch(void* const* d_in, const int* in_sizes, int n_in,
                              void* d_out, int out_size, void* d_ws, size_t ws_size,
                              hipStream_t stream) {
    const float* x = (const float*)d_in[0];
    const float* y = (const float*)d_in[1];
    const int* pos_num = (const int*)d_in[2];
    float* out = (float*)d_out;
    const int n = in_sizes[0];

    unsigned* ws = (unsigned*)d_ws;
    Ctrl* ctrl = (Ctrl*)d_ws;
    unsigned* cand = ws + CTRL_BYTES / 4;
    unsigned cap = (ws_size > (size_t)CTRL_BYTES)
                       ? (unsigned)((ws_size - CTRL_BYTES) / 4)
                       : 0u;

    unsigned* hist1 = ws + offsetof(Ctrl, hist1) / 4;
    unsigned* hist2 = ws + offsetof(Ctrl, hist2) / 4;
    unsigned* hist3 = ws + offsetof(Ctrl, hist3) / 4;
    unsigned* Kneg = ws + offsetof(Ctrl, Kneg) / 4;
    unsigned* b1o = ws + offsetof(Ctrl, b1) / 4;
    unsigned* r1o = ws + offsetof(Ctrl, r1) / 4;
    unsigned* b2o = ws + offsetof(Ctrl, b2) / 4;
    unsigned* r2o = ws + offsetof(Ctrl, r2) / 4;
    unsigned* b3o = ws + offsetof(Ctrl, b3) / 4;

    k_init<<<1, 1024, 0, stream>>>(ws, pos_num);
    k_hist1<<<1024, 256, 0, stream>>>(x, y, ctrl, n);
    k_scan<<<1, 256, 0, stream>>>(hist1, NBINS1, Kneg, b1o);
    k_compact<<<1024, 256, 0, stream>>>(x, y, ctrl, cand, cap, n);
    k_candhist<<<128, 256, 0, stream>>>(cand, ctrl, cap, 2);
    k_scan<<<1, 256, 0, stream>>>(hist2, NBINS2, r1o, b2o);
    k_candhist<<<128, 256, 0, stream>>>(cand, ctrl, cap, 3);
    k_scan<<<1, 256, 0, stream>>>(hist3, NBINS2, r2o, b3o);
    k_final<<<1, 1024, 0, stream>>>(cand, ctrl, cap, pos_num, out);
}

// Round 3
// 178.291 us; speedup vs baseline: 7.2194x; 1.7498x over previous
//
#include <hip/hip_runtime.h>
#include <math.h>

// OHNM loss: pos BCE sum + top-k(600000) negative softplus sum, mean over 800000.
// Exact radix-select on monotone uint32 key: level-1 = top-12-bit histogram over
// full array; level-2 = mid-10-bit histogram over compacted boundary-bin
// candidates (~143K); level-3 = exact pairwise rank over ~140 ties-bin keys.
//
// R3: parallel tail (k_final2 grid + tiny k_out) replacing 1-block k_final
// (was 135 us on 1 CU); rotated histogram merges to de-hotspot the contended
// global atomics; wave-shuffle reductions; __logf-based softplus.

#define NBINS1 4096
#define NBINS2 1024
#define CTRL_BYTES 32768
#define LBUF_CAP 4096
#define TINY_CAP 8192

struct Ctrl {
    unsigned hist1[NBINS1];   // top-12-bit histogram (negatives)
    unsigned hist2[NBINS2];   // mid-10-bit histogram (candidates)
    float    pos_sum;         // sum softplus(-x) over positives
    float    neg_sure;        // sum softplus(x), negatives with bin1 > b1
    float    neg_rest;        // sum softplus(x), bin1==b1 && mid10 > b2
    unsigned cand_count;
    unsigned cand2_count;
    unsigned Kneg;            // 3 * pos_num
    unsigned b1, c1, r1;      // level-1 scan out: bin, count-above, remaining rank
    unsigned b2, c2, r2;      // level-2 scan out
};

__device__ __forceinline__ unsigned f2key(float x) {
    unsigned u = __float_as_uint(x);
    return (u & 0x80000000u) ? ~u : (u | 0x80000000u);
}
__device__ __forceinline__ float key2f(unsigned k) {
    unsigned u = (k & 0x80000000u) ? (k & 0x7FFFFFFFu) : ~k;
    return __uint_as_float(u);
}
__device__ __forceinline__ float softplusf(float x) {
    return fmaxf(x, 0.0f) + __logf(1.0f + __expf(-fabsf(x)));
}
__device__ __forceinline__ float wred(float v) {
    v += __shfl_down(v, 32); v += __shfl_down(v, 16); v += __shfl_down(v, 8);
    v += __shfl_down(v, 4);  v += __shfl_down(v, 2);  v += __shfl_down(v, 1);
    return v;
}

// ---------------- init: zero control region, stash Kneg ----------------
__global__ void k_init(unsigned* ws, const int* __restrict__ pos_num) {
    for (int i = threadIdx.x; i < CTRL_BYTES / 4; i += blockDim.x) ws[i] = 0u;
    __syncthreads();
    if (threadIdx.x == 0) {
        Ctrl* c = (Ctrl*)ws;
        c->Kneg = (unsigned)(pos_num[0] * 3);
    }
}

// ---------------- pass 1: hist of top-12 key bits + pos_sum ----------------
__global__ __launch_bounds__(256)
void k_hist1(const float* __restrict__ x, const float* __restrict__ y,
             Ctrl* __restrict__ ctrl, int n) {
    __shared__ unsigned h[NBINS1];
    __shared__ float red;
    for (int i = threadIdx.x; i < NBINS1; i += 256) h[i] = 0u;
    if (threadIdx.x == 0) red = 0.0f;
    __syncthreads();

    float ps = 0.0f;
    const int n4 = n >> 2;
    const float4* x4 = (const float4*)x;
    const float4* y4 = (const float4*)y;
    const int stride = gridDim.x * blockDim.x;
    for (int i = blockIdx.x * blockDim.x + threadIdx.x; i < n4; i += stride) {
        float4 xv = x4[i];
        float4 yv = y4[i];
        if (yv.x > 0.0f) ps += softplusf(-xv.x); else atomicAdd(&h[f2key(xv.x) >> 20], 1u);
        if (yv.y > 0.0f) ps += softplusf(-xv.y); else atomicAdd(&h[f2key(xv.y) >> 20], 1u);
        if (yv.z > 0.0f) ps += softplusf(-xv.z); else atomicAdd(&h[f2key(xv.z) >> 20], 1u);
        if (yv.w > 0.0f) ps += softplusf(-xv.w); else atomicAdd(&h[f2key(xv.w) >> 20], 1u);
    }
    if (blockIdx.x == 0 && threadIdx.x == 0) {   // tail (n % 4)
        for (int i = n4 << 2; i < n; ++i) {
            float xs = x[i], ys = y[i];
            if (ys > 0.0f) ps += softplusf(-xs); else atomicAdd(&h[f2key(xs) >> 20], 1u);
        }
    }
    __syncthreads();
    ps = wred(ps);
    if ((threadIdx.x & 63) == 0) atomicAdd(&red, ps);
    // merge with per-block rotated bin order to avoid line hotspotting
    const unsigned rot = (blockIdx.x * 997u) & (NBINS1 - 1);
    for (int i = threadIdx.x; i < NBINS1; i += 256) {
        unsigned b = (i + rot) & (NBINS1 - 1);
        unsigned v = h[b];
        if (v) atomicAdd(&ctrl->hist1[b], v);
    }
    __syncthreads();
    if (threadIdx.x == 0) atomicAdd(&ctrl->pos_sum, red);
}

// ---------------- descending rank scan (1 block, 256 thr) ----------------
// finds first bin (descending) where cumulative count >= R.
// out3 = { bin, count_strictly_above, R - count_above }
__global__ __launch_bounds__(256)
void k_scan(const unsigned* __restrict__ hist, int nbins,
            const unsigned* __restrict__ rank_ptr, unsigned* __restrict__ out3) {
    __shared__ unsigned sums[256];
    const unsigned R = *rank_ptr;
    const int per = nbins / 256;
    const int t = threadIdx.x;
    unsigned local[16];
    unsigned s = 0;
    for (int j = 0; j < per; ++j) {
        local[j] = hist[nbins - 1 - (t * per + j)];
        s += local[j];
    }
    sums[t] = s;
    __syncthreads();
    for (int off = 1; off < 256; off <<= 1) {
        unsigned v = (t >= off) ? sums[t - off] : 0u;
        __syncthreads();
        sums[t] += v;
        __syncthreads();
    }
    const unsigned incl = sums[t];
    const unsigned excl = incl - s;
    if (excl < R && incl >= R) {
        unsigned cum = excl;
        for (int j = 0; j < per; ++j) {
            if (cum + local[j] >= R) {
                int d = t * per + j;
                out3[0] = (unsigned)(nbins - 1 - d);
                out3[1] = cum;
                out3[2] = R - cum;
                break;
            }
            cum += local[j];
        }
    }
}

// ---------------- pass 2: sure-sum (bin > b1) + compact candidates (bin==b1) --
__global__ __launch_bounds__(256)
void k_compact(const float* __restrict__ x, const float* __restrict__ y,
               Ctrl* __restrict__ ctrl, unsigned* __restrict__ cand,
               unsigned cap, int n) {
    __shared__ unsigned lbuf[LBUF_CAP];
    __shared__ unsigned lcount;
    __shared__ unsigned gbase;
    __shared__ float red;
    if (threadIdx.x == 0) { lcount = 0u; red = 0.0f; }
    __syncthreads();
    const unsigned b1 = ctrl->b1;
    float ns = 0.0f;
    const int n4 = n >> 2;
    const float4* x4 = (const float4*)x;
    const float4* y4 = (const float4*)y;
    const int stride = gridDim.x * blockDim.x;
    for (int i = blockIdx.x * blockDim.x + threadIdx.x; i < n4; i += stride) {
        float4 xv = x4[i];
        float4 yv = y4[i];
        float xs[4] = {xv.x, xv.y, xv.z, xv.w};
        float yss[4] = {yv.x, yv.y, yv.z, yv.w};
#pragma unroll
        for (int c = 0; c < 4; ++c) {
            if (yss[c] == 0.0f) {
                unsigned k = f2key(xs[c]);
                unsigned b = k >> 20;
                if (b > b1) {
                    ns += softplusf(xs[c]);
                } else if (b == b1) {
                    unsigned p = atomicAdd(&lcount, 1u);        // LDS atomic
                    if (p < LBUF_CAP) lbuf[p] = k;
                    else {  // overflow fallback (lambda ~140/block; never expected)
                        unsigned gi = atomicAdd(&ctrl->cand_count, 1u);
                        if (gi < cap) cand[gi] = k;
                    }
                }
            }
        }
    }
    if (blockIdx.x == 0 && threadIdx.x == 0) {   // tail
        for (int i = n4 << 2; i < n; ++i) {
            float xs = x[i], ys = y[i];
            if (ys == 0.0f) {
                unsigned k = f2key(xs);
                unsigned b = k >> 20;
                if (b > b1) ns += softplusf(xs);
                else if (b == b1) {
                    unsigned p = atomicAdd(&lcount, 1u);
                    if (p < LBUF_CAP) lbuf[p] = k;
                    else {
                        unsigned gi = atomicAdd(&ctrl->cand_count, 1u);
                        if (gi < cap) cand[gi] = k;
                    }
                }
            }
        }
    }
    __syncthreads();
    ns = wred(ns);
    if ((threadIdx.x & 63) == 0) atomicAdd(&red, ns);
    const unsigned m = lcount < LBUF_CAP ? lcount : LBUF_CAP;
    if (threadIdx.x == 0) gbase = atomicAdd(&ctrl->cand_count, m);  // ONE per block
    __syncthreads();
    for (unsigned i = threadIdx.x; i < m; i += 256) {
        unsigned gi = gbase + i;
        if (gi < cap) cand[gi] = lbuf[i];
    }
    if (threadIdx.x == 0) atomicAdd(&ctrl->neg_sure, red);
}

// ---------------- level-2 histogram of candidates (mid 10 bits) ------------
__global__ __launch_bounds__(256)
void k_candhist2(const unsigned* __restrict__ cand, Ctrl* __restrict__ ctrl,
                 unsigned cap) {
    __shared__ unsigned h[NBINS2];
    for (int i = threadIdx.x; i < NBINS2; i += 256) h[i] = 0u;
    __syncthreads();
    const unsigned m0 = ctrl->cand_count;
    const unsigned m = m0 < cap ? m0 : cap;
    const unsigned stride = gridDim.x * blockDim.x;
    for (unsigned i = blockIdx.x * blockDim.x + threadIdx.x; i < m; i += stride) {
        atomicAdd(&h[(cand[i] >> 10) & 1023u], 1u);
    }
    __syncthreads();
    const unsigned rot = (blockIdx.x * 41u) & (NBINS2 - 1);
    for (int i = threadIdx.x; i < NBINS2; i += 256) {
        unsigned b = (i + rot) & (NBINS2 - 1);
        unsigned v = h[b];
        if (v) atomicAdd(&ctrl->hist2[b], v);
    }
}

// ------ parallel final: sum softplus(mid > b2); compact mid==b2 -> cand2 ----
__global__ __launch_bounds__(256)
void k_final2(const unsigned* __restrict__ cand, Ctrl* __restrict__ ctrl,
              unsigned cap, unsigned* __restrict__ cand2) {
    __shared__ float red;
    if (threadIdx.x == 0) red = 0.0f;
    __syncthreads();
    const unsigned m0 = ctrl->cand_count;
    const unsigned m = m0 < cap ? m0 : cap;
    const unsigned b2 = ctrl->b2;
    float s = 0.0f;
    const unsigned stride = gridDim.x * blockDim.x;
    for (unsigned i = blockIdx.x * blockDim.x + threadIdx.x; i < m; i += stride) {
        unsigned k = cand[i];
        unsigned mid = (k >> 10) & 1023u;
        if (mid > b2) {
            s += softplusf(key2f(k));
        } else if (mid == b2) {   // ~140 total across grid: direct global atomic ok
            unsigned gi = atomicAdd(&ctrl->cand2_count, 1u);
            if (gi < TINY_CAP) cand2[gi] = k;
        }
    }
    s = wred(s);
    if ((threadIdx.x & 63) == 0) atomicAdd(&red, s);
    __syncthreads();
    if (threadIdx.x == 0) atomicAdd(&ctrl->neg_rest, red);
}

// ------ out: exact top-r2 among ties-bin keys (pairwise rank), combine ------
__global__ __launch_bounds__(256)
void k_out(const unsigned* __restrict__ cand2, Ctrl* __restrict__ ctrl,
           const int* __restrict__ pos_num, float* __restrict__ out) {
    __shared__ unsigned sh[TINY_CAP];
    __shared__ float red;
    const unsigned m0 = ctrl->cand2_count;
    const unsigned m3 = m0 < TINY_CAP ? m0 : TINY_CAP;
    const unsigned r2 = ctrl->r2;
    if (threadIdx.x == 0) red = 0.0f;
    for (unsigned i = threadIdx.x; i < m3; i += 256) sh[i] = cand2[i];
    __syncthreads();
    float s = 0.0f;
    for (unsigned i = threadIdx.x; i < m3; i += 256) {
        unsigned k = sh[i];
        unsigned rank = 0;
        for (unsigned j = 0; j < m3; ++j) {
            unsigned kj = sh[j];
            rank += (kj > k) || (kj == k && j < i);
        }
        if (rank < r2) s += softplusf(key2f(k));
    }
    s = wred(s);
    if ((threadIdx.x & 63) == 0) atomicAdd(&red, s);
    __syncthreads();
    if (threadIdx.x == 0) {
        int p = pos_num[0];
        float total = ctrl->pos_sum + ctrl->neg_sure + ctrl->neg_rest + red;
        out[0] = total / (float)(4 * p);
    }
}

extern "C" void kernel_launch(void* const* d_in, const int* in_sizes, int n_in,
                              void* d_out, int out_size, void* d_ws, size_t ws_size,
                              hipStream_t stream) {
    const float* x = (const float*)d_in[0];
    const float* y = (const float*)d_in[1];
    const int* pos_num = (const int*)d_in[2];
    float* out = (float*)d_out;
    const int n = in_sizes[0];

    unsigned* ws = (unsigned*)d_ws;
    Ctrl* ctrl = (Ctrl*)d_ws;
    unsigned* cand2 = ws + CTRL_BYTES / 4;              // TINY_CAP words
    unsigned* cand = cand2 + TINY_CAP;
    const size_t reserved = (size_t)CTRL_BYTES + (size_t)TINY_CAP * 4;
    unsigned cap = (ws_size > reserved) ? (unsigned)((ws_size - reserved) / 4) : 0u;

    unsigned* hist1 = ws + offsetof(Ctrl, hist1) / 4;
    unsigned* hist2 = ws + offsetof(Ctrl, hist2) / 4;
    unsigned* Kneg = ws + offsetof(Ctrl, Kneg) / 4;
    unsigned* b1o = ws + offsetof(Ctrl, b1) / 4;
    unsigned* r1o = ws + offsetof(Ctrl, r1) / 4;
    unsigned* b2o = ws + offsetof(Ctrl, b2) / 4;

    k_init<<<1, 1024, 0, stream>>>(ws, pos_num);
    k_hist1<<<1024, 256, 0, stream>>>(x, y, ctrl, n);
    k_scan<<<1, 256, 0, stream>>>(hist1, NBINS1, Kneg, b1o);
    k_compact<<<1024, 256, 0, stream>>>(x, y, ctrl, cand, cap, n);
    k_candhist2<<<128, 256, 0, stream>>>(cand, ctrl, cap);
    k_scan<<<1, 256, 0, stream>>>(hist2, NBINS2, r1o, b2o);
    k_final2<<<256, 256, 0, stream>>>(cand, ctrl, cap, cand2);
    k_out<<<1, 256, 0, stream>>>(cand2, ctrl, pos_num, out);
}